// Round 1
// baseline (1679.534 us; speedup 1.0000x reference)
//
#include <hip/hip_runtime.h>

// Problem constants: x(2,4096,4096) fp32, W(16384,4096) fp32, bias(16384) fp32
// y = alpha*(x @ Q^T) + bias, alpha = mean|W|, Q ternary.
#define M_DIM 8192
#define N_DIM 16384
#define K_DIM 4096

typedef unsigned short u16;
typedef unsigned int u32;
typedef __attribute__((ext_vector_type(8))) short bf16x8;
typedef __attribute__((ext_vector_type(8))) unsigned short u16x8;
typedef __attribute__((ext_vector_type(4))) float f32x4;

__device__ __forceinline__ void gload16(const void* g, void* l) {
  __builtin_amdgcn_global_load_lds((const __attribute__((address_space(1))) void*)g,
                                   (__attribute__((address_space(3))) void*)l,
                                   16, 0, 0);
}

// ---------------- alpha = mean(|W|), f64 two-pass reduction ----------------
__global__ void reduce_abs1(const float* __restrict__ w, double* __restrict__ partials) {
  const float4* w4 = (const float4*)w;
  size_t base = (size_t)blockIdx.x * 4096 + threadIdx.x;  // float4 units
  double s = 0.0;
#pragma unroll
  for (int i = 0; i < 16; ++i) {
    float4 v = w4[base + (size_t)i * 256];
    s += (double)fabsf(v.x); s += (double)fabsf(v.y);
    s += (double)fabsf(v.z); s += (double)fabsf(v.w);
  }
#pragma unroll
  for (int off = 32; off > 0; off >>= 1) s += __shfl_down(s, off, 64);
  __shared__ double red[4];
  int wv = threadIdx.x >> 6, lane = threadIdx.x & 63;
  if (lane == 0) red[wv] = s;
  __syncthreads();
  if (threadIdx.x == 0) partials[blockIdx.x] = (red[0] + red[1]) + (red[2] + red[3]);
}

__global__ void reduce_abs2(const double* __restrict__ partials,
                            double* __restrict__ alpha_d, float* __restrict__ alpha_f) {
  double s = 0.0;
  for (int i = threadIdx.x; i < 4096; i += 256) s += partials[i];
#pragma unroll
  for (int off = 32; off > 0; off >>= 1) s += __shfl_down(s, off, 64);
  __shared__ double red[4];
  int wv = threadIdx.x >> 6, lane = threadIdx.x & 63;
  if (lane == 0) red[wv] = s;
  __syncthreads();
  if (threadIdx.x == 0) {
    double total = (red[0] + red[1]) + (red[2] + red[3]);
    double a = total / (double)((long long)N_DIM * (long long)K_DIM);
    alpha_d[0] = a;
    alpha_f[0] = (float)a;
  }
}

// ---------------- W -> ternary Q stored as bf16 (+1/0/-1 exact) ----------------
__global__ void quant_w(const float* __restrict__ w, const double* __restrict__ alpha_d,
                        u16* __restrict__ q) {
  double inv = 1.0 / alpha_d[0];
  size_t i8 = (size_t)blockIdx.x * 256 + threadIdx.x;  // unit of 8 elements
  const float4* w4 = (const float4*)w;
  float4 v0 = w4[i8 * 2], v1 = w4[i8 * 2 + 1];
  float vv[8] = {v0.x, v0.y, v0.z, v0.w, v1.x, v1.y, v1.z, v1.w};
  u16x8 o;
#pragma unroll
  for (int j = 0; j < 8; ++j) {
    double r = rint((double)vv[j] * inv);   // round-to-nearest-even like np/jnp.round
    u16 enc = 0;
    if (r >= 1.0) enc = 0x3F80u;            // +1.0 bf16
    else if (r <= -1.0) enc = 0xBF80u;      // -1.0 bf16
    o[j] = enc;
  }
  *((u16x8*)q + i8) = o;
}

// ---------------- x fp32 -> bf16 (RNE) ----------------
__global__ void conv_x(const float* __restrict__ x, u16* __restrict__ xb) {
  size_t i8 = (size_t)blockIdx.x * 256 + threadIdx.x;
  const float4* x4 = (const float4*)x;
  float4 v0 = x4[i8 * 2], v1 = x4[i8 * 2 + 1];
  float vv[8] = {v0.x, v0.y, v0.z, v0.w, v1.x, v1.y, v1.z, v1.w};
  u16x8 o;
#pragma unroll
  for (int j = 0; j < 8; ++j) {
    u32 u = __float_as_uint(vv[j]);
    u += 0x7FFFu + ((u >> 16) & 1u);        // RNE
    o[j] = (u16)(u >> 16);
  }
  *((u16x8*)xb + i8) = o;
}

// ---------------- bf16 GEMM: C[m][n] = alpha * sum_k A[m][k]*Bq[n][k] + bias[n] ----------------
// 128x128 tile, BK=64, 256 threads (4 waves, 2x2 of 64x64), mfma_f32_16x16x32_bf16.
// LDS XOR chunk-swizzle (T2-style, both-sides: pre-swizzled global source + swizzled ds_read).
__global__ __launch_bounds__(256) void gemm_bf16(
    const u16* __restrict__ A, const u16* __restrict__ Bq,
    const float* __restrict__ bias, const float* __restrict__ alpha_f,
    float* __restrict__ C) {
  __shared__ u16 Alds[128 * 64];  // 16 KiB
  __shared__ u16 Blds[128 * 64];  // 16 KiB

  const int t = threadIdx.x;
  const int wv = t >> 6, l = t & 63;
  const int wr = wv >> 1, wc = wv & 1;   // wave 2x2 grid over 128x128
  const int lr = l & 15, lk = l >> 4;

  // XCD-bijective swizzle (8192 % 8 == 0) + GROUP_M=4 for L2 reuse of B panels
  const int bid = blockIdx.x;
  const int wg = (bid & 7) * 1024 + (bid >> 3);
  const int grp = wg >> 9;            // / (4*128)
  const int rem = wg & 511;
  const int tm = grp * 4 + (rem & 3); // 0..63
  const int tn = rem >> 2;            // 0..127

  const u16* Ag = A + (size_t)(tm * 128) * K_DIM;
  const u16* Bg = Bq + (size_t)(tn * 128) * K_DIM;

  // Staging: physical 16B chunk q holds logical chunk c = (q&7)^(row&7) of row q>>3.
  int off[4];
#pragma unroll
  for (int i = 0; i < 4; ++i) {
    int q = i * 256 + t;
    int row = q >> 3;
    int c = (q & 7) ^ (row & 7);
    off[i] = row * K_DIM + c * 8;     // element offset from panel base (+= kt*64 per step)
  }

  // LDS read chunk indices (constant across K loop; swizzle applied on read side too)
  int ach[4][2], bch[4][2];
#pragma unroll
  for (int mi = 0; mi < 4; ++mi) {
    int rA = wr * 64 + mi * 16 + lr;
    int rB = wc * 64 + mi * 16 + lr;
#pragma unroll
    for (int ks = 0; ks < 2; ++ks) {
      int c = ks * 4 + lk;
      ach[mi][ks] = rA * 8 + (c ^ (rA & 7));
      bch[mi][ks] = rB * 8 + (c ^ (rB & 7));
    }
  }

  f32x4 acc[4][4];
#pragma unroll
  for (int mi = 0; mi < 4; ++mi)
#pragma unroll
    for (int ni = 0; ni < 4; ++ni)
      acc[mi][ni] = (f32x4){0.f, 0.f, 0.f, 0.f};

  for (int kt = 0; kt < K_DIM / 64; ++kt) {
    const int k0 = kt * 64;
#pragma unroll
    for (int i = 0; i < 4; ++i) {
      gload16(Ag + off[i] + k0, &Alds[(i * 256 + wv * 64) * 8]);
      gload16(Bg + off[i] + k0, &Blds[(i * 256 + wv * 64) * 8]);
    }
    __syncthreads();  // drains vmcnt(0) -> LDS tiles complete
#pragma unroll
    for (int ks = 0; ks < 2; ++ks) {
      bf16x8 av[4], bv[4];
#pragma unroll
      for (int mi = 0; mi < 4; ++mi) av[mi] = *(const bf16x8*)&Alds[ach[mi][ks] * 8];
#pragma unroll
      for (int ni = 0; ni < 4; ++ni) bv[ni] = *(const bf16x8*)&Blds[bch[ni][ks] * 8];
#pragma unroll
      for (int mi = 0; mi < 4; ++mi)
#pragma unroll
        for (int ni = 0; ni < 4; ++ni)
          acc[mi][ni] = __builtin_amdgcn_mfma_f32_16x16x32_bf16(av[mi], bv[ni], acc[mi][ni], 0, 0, 0);
    }
    __syncthreads();  // safe to overwrite LDS next iter
  }

  // Epilogue: y = alpha*acc + bias.  C/D layout: col = l&15, row = 4*(l>>4)+j (m89-verified).
  const float alpha = alpha_f[0];
#pragma unroll
  for (int ni = 0; ni < 4; ++ni) {
    const int col = tn * 128 + wc * 64 + ni * 16 + lr;
    const float bs = bias[col];
#pragma unroll
    for (int mi = 0; mi < 4; ++mi) {
      const int row = tm * 128 + wr * 64 + mi * 16 + lk * 4;
      float* Cp = C + (size_t)row * N_DIM + col;
#pragma unroll
      for (int j = 0; j < 4; ++j)
        Cp[(size_t)j * N_DIM] = alpha * acc[mi][ni][j] + bs;
    }
  }
}

extern "C" void kernel_launch(void* const* d_in, const int* in_sizes, int n_in,
                              void* d_out, int out_size, void* d_ws, size_t ws_size,
                              hipStream_t stream) {
  const float* x = (const float*)d_in[0];     // 33,554,432
  const float* w = (const float*)d_in[1];     // 67,108,864
  const float* bias = (const float*)d_in[2];  // 16,384
  float* out = (float*)d_out;                 // 134,217,728 fp32

  char* ws = (char*)d_ws;
  double* alpha_d = (double*)ws;                       // [0,8)
  float* alpha_f = (float*)(ws + 8);                   // [8,12)
  double* partials = (double*)(ws + 16);               // [16, 16+32768)
  u16* xb = (u16*)(ws + 65536);                        // 64 MiB  (M*K bf16)
  u16* qb = (u16*)(ws + 65536 + 67108864ULL);          // 128 MiB (N*K bf16)
  // total ws need ~192.06 MiB

  reduce_abs1<<<4096, 256, 0, stream>>>(w, partials);
  reduce_abs2<<<1, 256, 0, stream>>>(partials, alpha_d, alpha_f);
  quant_w<<<32768, 256, 0, stream>>>(w, alpha_d, qb);
  conv_x<<<16384, 256, 0, stream>>>(x, xb);
  gemm_bf16<<<8192, 256, 0, stream>>>(xb, qb, bias, alpha_f, out);
}

// Round 2
// 1412.596 us; speedup vs baseline: 1.1890x; 1.1890x over previous
//
#include <hip/hip_runtime.h>

// y = alpha*(x @ Q^T) + bias; alpha = mean|W|; Q = clip(round(W/alpha),-1,1)
// x:(2,4096,4096) f32, W:(16384,4096) f32, bias:(16384) f32, out f32.
#define M_DIM 8192
#define N_DIM 16384
#define K_DIM 4096
#define NT 64  // K_DIM / 64

typedef unsigned short u16;
typedef unsigned int u32;
typedef __attribute__((ext_vector_type(8))) short bf16x8;
typedef __attribute__((ext_vector_type(8))) unsigned short u16x8;
typedef __attribute__((ext_vector_type(4))) float f32x4;

#define MFMA(a, b, c) __builtin_amdgcn_mfma_f32_16x16x32_bf16(a, b, c, 0, 0, 0)

__device__ __forceinline__ void gload16(const u16* g, u16* l) {
  __builtin_amdgcn_global_load_lds((const __attribute__((address_space(1))) void*)g,
                                   (__attribute__((address_space(3))) void*)l, 16, 0, 0);
}

// ---------------- alpha = mean(|W|), f64 two-pass reduction ----------------
__global__ void reduce_abs1(const float* __restrict__ w, double* __restrict__ partials) {
  const float4* w4 = (const float4*)w;
  size_t base = (size_t)blockIdx.x * 4096 + threadIdx.x;
  double s = 0.0;
#pragma unroll
  for (int i = 0; i < 16; ++i) {
    float4 v = w4[base + (size_t)i * 256];
    s += (double)fabsf(v.x); s += (double)fabsf(v.y);
    s += (double)fabsf(v.z); s += (double)fabsf(v.w);
  }
#pragma unroll
  for (int off = 32; off > 0; off >>= 1) s += __shfl_down(s, off, 64);
  __shared__ double red[4];
  int wv = threadIdx.x >> 6, lane = threadIdx.x & 63;
  if (lane == 0) red[wv] = s;
  __syncthreads();
  if (threadIdx.x == 0) partials[blockIdx.x] = (red[0] + red[1]) + (red[2] + red[3]);
}

__global__ void reduce_abs2(const double* __restrict__ partials,
                            double* __restrict__ alpha_d, float* __restrict__ alpha_f) {
  double s = 0.0;
  for (int i = threadIdx.x; i < 4096; i += 256) s += partials[i];
#pragma unroll
  for (int off = 32; off > 0; off >>= 1) s += __shfl_down(s, off, 64);
  __shared__ double red[4];
  int wv = threadIdx.x >> 6, lane = threadIdx.x & 63;
  if (lane == 0) red[wv] = s;
  __syncthreads();
  if (threadIdx.x == 0) {
    double total = (red[0] + red[1]) + (red[2] + red[3]);
    double a = total / (double)((long long)N_DIM * (long long)K_DIM);
    alpha_d[0] = a;
    alpha_f[0] = (float)a;
  }
}

// ---------------- W -> ternary Q stored as bf16 (+1/0/-1 exact) ----------------
__global__ void quant_w(const float* __restrict__ w, const double* __restrict__ alpha_d,
                        u16* __restrict__ q) {
  double inv = 1.0 / alpha_d[0];
  size_t i8 = (size_t)blockIdx.x * 256 + threadIdx.x;
  const float4* w4 = (const float4*)w;
  float4 v0 = w4[i8 * 2], v1 = w4[i8 * 2 + 1];
  float vv[8] = {v0.x, v0.y, v0.z, v0.w, v1.x, v1.y, v1.z, v1.w};
  u16x8 o;
#pragma unroll
  for (int j = 0; j < 8; ++j) {
    double r = rint((double)vv[j] * inv);
    u16 enc = 0;
    if (r >= 1.0) enc = 0x3F80u;
    else if (r <= -1.0) enc = 0xBF80u;
    o[j] = enc;
  }
  *((u16x8*)q + i8) = o;
}

// ---------------- x fp32 -> bf16 (RNE) ----------------
__global__ void conv_x(const float* __restrict__ x, u16* __restrict__ xb) {
  size_t i8 = (size_t)blockIdx.x * 256 + threadIdx.x;
  const float4* x4 = (const float4*)x;
  float4 v0 = x4[i8 * 2], v1 = x4[i8 * 2 + 1];
  float vv[8] = {v0.x, v0.y, v0.z, v0.w, v1.x, v1.y, v1.z, v1.w};
  u16x8 o;
#pragma unroll
  for (int j = 0; j < 8; ++j) {
    u32 u = __float_as_uint(vv[j]);
    u += 0x7FFFu + ((u >> 16) & 1u);
    o[j] = (u16)(u >> 16);
  }
  *((u16x8*)xb + i8) = o;
}

// ---------------- 256x256-tile 8-phase bf16 GEMM (T2+T3+T4+T5) ----------------
// 512 threads = 8 waves (2M x 4N); per-wave 128x64 output = acc[8][4] f32x4.
// LDS: 2 tile-buffers x {A 256x64, B 256x64} bf16 = 128 KiB.
// Half-tiles per K-tile: [B0,B1,A0,A1]; phase P stages global half P+7.
// All LDS reads of a tile happen in its phases 0-1; overwrites land >=1 barrier
// after the region's last read. vmcnt(6) once per tile (3 halves in flight),
// vmcnt(0) for the last two tiles (prefetches skipped there).
__global__ __launch_bounds__(512, 2) void gemm256(
    const u16* __restrict__ A, const u16* __restrict__ Bq,
    const float* __restrict__ bias, const float* __restrict__ alpha_f,
    float* __restrict__ C) {
  __shared__ __align__(16) u16 Alds[2][2][128 * 64];  // [parity][half][r*64+k]
  __shared__ __align__(16) u16 Blds[2][2][128 * 64];

  const int t = threadIdx.x;
  const int wv = t >> 6, l = t & 63;
  const int wr = wv >> 2, wc = wv & 3;  // 2M x 4N wave grid
  const int lr = l & 15, lk = l >> 4;

  // XCD-bijective swizzle (2048 % 8 == 0) + 8(tm) x 64(tn) supertiles
  const int bid = blockIdx.x;
  const int wg = (bid & 7) * 256 + (bid >> 3);
  const int grp = wg >> 9, rem = wg & 511;
  const int tm = grp * 8 + (rem & 7);  // 0..31
  const int tn = rem >> 3;             // 0..63

  const u16* Ag = A + (size_t)tm * 256 * K_DIM;
  const u16* Bg = Bq + (size_t)tn * 256 * K_DIM;

  // staging source offsets (pre-swizzled global source, linear LDS dest)
  const int q0 = t, q1 = 512 + t;
  const int r0 = q0 >> 3, c0 = (q0 & 7) ^ (r0 & 7);
  const int r1 = q1 >> 3, c1 = (q1 & 7) ^ (r1 & 7);
  const size_t so0 = (size_t)r0 * K_DIM + c0 * 8;
  const size_t so1 = (size_t)r1 * K_DIM + c1 * 8;
  const int do0 = (wv * 64) * 8;          // u16 units (wave-uniform dest base)
  const int do1 = (512 + wv * 64) * 8;

  // LDS read offsets (u16 units), swizzled to match staging
  int aoff[8][2], boff[4][2];
#pragma unroll
  for (int mi = 0; mi < 8; ++mi) {
    int r = mi * 16 + lr;
#pragma unroll
    for (int ks = 0; ks < 2; ++ks)
      aoff[mi][ks] = (r * 8 + ((ks * 4 + lk) ^ (r & 7))) * 8;
  }
#pragma unroll
  for (int ni = 0; ni < 4; ++ni) {
    int r = (wc & 1) * 64 + ni * 16 + lr;
#pragma unroll
    for (int ks = 0; ks < 2; ++ks)
      boff[ni][ks] = (r * 8 + ((ks * 4 + lk) ^ (r & 7))) * 8;
  }

  f32x4 acc[8][4];
#pragma unroll
  for (int mi = 0; mi < 8; ++mi)
#pragma unroll
    for (int ni = 0; ni < 4; ++ni)
      acc[mi][ni] = (f32x4){0.f, 0.f, 0.f, 0.f};

  // stage one half-tile H (2 x global_load_lds per wave); skipped past last tile
  auto stage = [&](int H) {
    int g = H >> 2;
    if (g < NT) {
      int sub = H & 3;  // 0:B0 1:B1 2:A0 3:A1
      const u16* src;
      u16* dst;
      if (sub < 2) { src = Bg + (size_t)sub * (128 * K_DIM); dst = &Blds[g & 1][sub][0]; }
      else         { src = Ag + (size_t)(sub - 2) * (128 * K_DIM); dst = &Alds[g & 1][sub - 2][0]; }
      src += g * 64;
      gload16(src + so0, dst + do0);
      gload16(src + so1, dst + do1);
    }
  };

  // prologue: issue halves 0..6 (tile0 complete + 3 halves of tile1 in flight)
#pragma unroll
  for (int H = 0; H < 7; ++H) stage(H);
  asm volatile("s_waitcnt vmcnt(6)" ::: "memory");
  __builtin_amdgcn_s_barrier();

  for (int kt = 0; kt < NT; ++kt) {
    const int par = kt & 1;
    const u16* Ar = &Alds[par][wr][0];
    const u16* Br = &Blds[par][wc >> 1][0];

    // ---- phase 0: read B(8) + A mi{0,1}(4); stage A1(kt+1); MFMA mi{0,1} ----
    bf16x8 bv[4][2], a0[2][2];
#pragma unroll
    for (int ni = 0; ni < 4; ++ni)
#pragma unroll
      for (int ks = 0; ks < 2; ++ks)
        bv[ni][ks] = *(const bf16x8*)(Br + boff[ni][ks]);
#pragma unroll
    for (int mi = 0; mi < 2; ++mi)
#pragma unroll
      for (int ks = 0; ks < 2; ++ks)
        a0[mi][ks] = *(const bf16x8*)(Ar + aoff[mi][ks]);
    stage(4 * kt + 7);
    __builtin_amdgcn_s_barrier();
    asm volatile("s_waitcnt lgkmcnt(0)" ::: "memory");
    __builtin_amdgcn_s_setprio(1);
#pragma unroll
    for (int ks = 0; ks < 2; ++ks)
#pragma unroll
      for (int mi = 0; mi < 2; ++mi)
#pragma unroll
        for (int ni = 0; ni < 4; ++ni)
          acc[mi][ni] = MFMA(a0[mi][ks], bv[ni][ks], acc[mi][ni]);
    __builtin_amdgcn_s_setprio(0);
    __builtin_amdgcn_s_barrier();

    // ---- phase 1: read A mi{2..7}(12); stage B0(kt+2); MFMA mi{2,3} ----
    bf16x8 a2[6][2];
#pragma unroll
    for (int m = 0; m < 6; ++m)
#pragma unroll
      for (int ks = 0; ks < 2; ++ks)
        a2[m][ks] = *(const bf16x8*)(Ar + aoff[2 + m][ks]);
    stage(4 * kt + 8);
    __builtin_amdgcn_s_barrier();
    asm volatile("s_waitcnt lgkmcnt(0)" ::: "memory");
    __builtin_amdgcn_s_setprio(1);
#pragma unroll
    for (int ks = 0; ks < 2; ++ks)
#pragma unroll
      for (int m = 0; m < 2; ++m)
#pragma unroll
        for (int ni = 0; ni < 4; ++ni)
          acc[2 + m][ni] = MFMA(a2[m][ks], bv[ni][ks], acc[2 + m][ni]);
    __builtin_amdgcn_s_setprio(0);
    __builtin_amdgcn_s_barrier();

    // ---- phase 2: stage B1(kt+2); MFMA mi{4,5} ----
    stage(4 * kt + 9);
    __builtin_amdgcn_s_barrier();
    __builtin_amdgcn_s_setprio(1);
#pragma unroll
    for (int ks = 0; ks < 2; ++ks)
#pragma unroll
      for (int m = 0; m < 2; ++m)
#pragma unroll
        for (int ni = 0; ni < 4; ++ni)
          acc[4 + m][ni] = MFMA(a2[2 + m][ks], bv[ni][ks], acc[4 + m][ni]);
    __builtin_amdgcn_s_setprio(0);
    __builtin_amdgcn_s_barrier();

    // ---- phase 3: stage A0(kt+2); MFMA mi{6,7}; counted vmcnt; barrier ----
    stage(4 * kt + 10);
    __builtin_amdgcn_s_barrier();
    __builtin_amdgcn_s_setprio(1);
#pragma unroll
    for (int ks = 0; ks < 2; ++ks)
#pragma unroll
      for (int m = 0; m < 2; ++m)
#pragma unroll
        for (int ni = 0; ni < 4; ++ni)
          acc[6 + m][ni] = MFMA(a2[4 + m][ks], bv[ni][ks], acc[6 + m][ni]);
    __builtin_amdgcn_s_setprio(0);
    if (kt < NT - 2) asm volatile("s_waitcnt vmcnt(6)" ::: "memory");
    else             asm volatile("s_waitcnt vmcnt(0)" ::: "memory");
    __builtin_amdgcn_s_barrier();
  }

  // epilogue: y = alpha*acc + bias.  C/D: col=l&15, row=4*(l>>4)+j (m89-verified)
  const float alpha = alpha_f[0];
#pragma unroll
  for (int ni = 0; ni < 4; ++ni) {
    const int col = tn * 256 + wc * 64 + ni * 16 + lr;
    const float bs = bias[col];
#pragma unroll
    for (int mi = 0; mi < 8; ++mi) {
      const int row = tm * 256 + wr * 128 + mi * 16 + lk * 4;
      float* Cp = C + (size_t)row * N_DIM + col;
#pragma unroll
      for (int j = 0; j < 4; ++j)
        Cp[(size_t)j * N_DIM] = alpha * acc[mi][ni][j] + bs;
    }
  }
}

extern "C" void kernel_launch(void* const* d_in, const int* in_sizes, int n_in,
                              void* d_out, int out_size, void* d_ws, size_t ws_size,
                              hipStream_t stream) {
  const float* x = (const float*)d_in[0];
  const float* w = (const float*)d_in[1];
  const float* bias = (const float*)d_in[2];
  float* out = (float*)d_out;

  char* ws = (char*)d_ws;
  double* alpha_d = (double*)ws;
  float* alpha_f = (float*)(ws + 8);
  double* partials = (double*)(ws + 16);
  u16* xb = (u16*)(ws + 65536);                 // 64 MiB (M*K bf16)
  u16* qb = (u16*)(ws + 65536 + 67108864ULL);   // 128 MiB (N*K bf16)

  reduce_abs1<<<4096, 256, 0, stream>>>(w, partials);
  reduce_abs2<<<1, 256, 0, stream>>>(partials, alpha_d, alpha_f);
  quant_w<<<32768, 256, 0, stream>>>(w, alpha_d, qb);
  conv_x<<<16384, 256, 0, stream>>>(x, xb);
  gemm256<<<2048, 512, 0, stream>>>(xb, qb, bias, alpha_f, out);
}

// Round 3
// 1244.941 us; speedup vs baseline: 1.3491x; 1.1347x over previous
//
#include <hip/hip_runtime.h>

// y = alpha*(x @ Q^T) + bias; alpha = mean|W|; Q = clip(round(W/alpha),-1,1)
// x:(2,4096,4096) f32, W:(16384,4096) f32, bias:(16384) f32, out f32.
#define M_DIM 8192
#define N_DIM 16384
#define K_DIM 4096
#define NT 64  // K_DIM / 64

typedef unsigned short u16;
typedef unsigned int u32;
typedef __attribute__((ext_vector_type(8))) short bf16x8;
typedef __attribute__((ext_vector_type(8))) unsigned short u16x8;
typedef __attribute__((ext_vector_type(4))) float f32x4;

#define MFMA(a, b, c) __builtin_amdgcn_mfma_f32_16x16x32_bf16(a, b, c, 0, 0, 0)

__device__ __forceinline__ void gload16(const u16* g, u16* l) {
  __builtin_amdgcn_global_load_lds((const __attribute__((address_space(1))) void*)g,
                                   (__attribute__((address_space(3))) void*)l, 16, 0, 0);
}

// ---------------- alpha = mean(|W|), f64 two-pass reduction ----------------
__global__ void reduce_abs1(const float* __restrict__ w, double* __restrict__ partials) {
  const float4* w4 = (const float4*)w;
  size_t base = (size_t)blockIdx.x * 4096 + threadIdx.x;
  double s = 0.0;
#pragma unroll
  for (int i = 0; i < 16; ++i) {
    float4 v = w4[base + (size_t)i * 256];
    s += (double)fabsf(v.x); s += (double)fabsf(v.y);
    s += (double)fabsf(v.z); s += (double)fabsf(v.w);
  }
#pragma unroll
  for (int off = 32; off > 0; off >>= 1) s += __shfl_down(s, off, 64);
  __shared__ double red[4];
  int wv = threadIdx.x >> 6, lane = threadIdx.x & 63;
  if (lane == 0) red[wv] = s;
  __syncthreads();
  if (threadIdx.x == 0) partials[blockIdx.x] = (red[0] + red[1]) + (red[2] + red[3]);
}

__global__ void reduce_abs2(const double* __restrict__ partials,
                            double* __restrict__ alpha_d, float* __restrict__ alpha_f) {
  double s = 0.0;
  for (int i = threadIdx.x; i < 4096; i += 256) s += partials[i];
#pragma unroll
  for (int off = 32; off > 0; off >>= 1) s += __shfl_down(s, off, 64);
  __shared__ double red[4];
  int wv = threadIdx.x >> 6, lane = threadIdx.x & 63;
  if (lane == 0) red[wv] = s;
  __syncthreads();
  if (threadIdx.x == 0) {
    double total = (red[0] + red[1]) + (red[2] + red[3]);
    double a = total / (double)((long long)N_DIM * (long long)K_DIM);
    alpha_d[0] = a;
    alpha_f[0] = (float)a;
  }
}

// ---------------- W -> ternary Q stored as bf16 (+1/0/-1 exact) ----------------
__global__ void quant_w(const float* __restrict__ w, const double* __restrict__ alpha_d,
                        u16* __restrict__ q) {
  double inv = 1.0 / alpha_d[0];
  size_t i8 = (size_t)blockIdx.x * 256 + threadIdx.x;
  const float4* w4 = (const float4*)w;
  float4 v0 = w4[i8 * 2], v1 = w4[i8 * 2 + 1];
  float vv[8] = {v0.x, v0.y, v0.z, v0.w, v1.x, v1.y, v1.z, v1.w};
  u16x8 o;
#pragma unroll
  for (int j = 0; j < 8; ++j) {
    double r = rint((double)vv[j] * inv);
    u16 enc = 0;
    if (r >= 1.0) enc = 0x3F80u;
    else if (r <= -1.0) enc = 0xBF80u;
    o[j] = enc;
  }
  *((u16x8*)q + i8) = o;
}

// ---------------- x fp32 -> bf16 (RNE) ----------------
__global__ void conv_x(const float* __restrict__ x, u16* __restrict__ xb) {
  size_t i8 = (size_t)blockIdx.x * 256 + threadIdx.x;
  const float4* x4 = (const float4*)x;
  float4 v0 = x4[i8 * 2], v1 = x4[i8 * 2 + 1];
  float vv[8] = {v0.x, v0.y, v0.z, v0.w, v1.x, v1.y, v1.z, v1.w};
  u16x8 o;
#pragma unroll
  for (int j = 0; j < 8; ++j) {
    u32 u = __float_as_uint(vv[j]);
    u += 0x7FFFu + ((u >> 16) & 1u);
    o[j] = (u16)(u >> 16);
  }
  *((u16x8*)xb + i8) = o;
}

// ---------------- 256x256-tile 8-phase bf16 GEMM (T2+T3+T4+T5) ----------------
// 512 threads = 8 waves (2M x 4N); per-wave 128x64 output = acc[8][4] f32x4.
// LDS: 2 tile-buffers x {A 256x64, B 256x64} bf16 = 128 KiB.
// Reads per phase {12,8,4,0}: each phase's MFMA uses frags read <=1 phase back.
// Stage per phase: {A1(kt+1), B0(kt+2), B1(kt+2), A0(kt+2)}; A-half reads end
// at P2 so A0(kt+2)@P3 lands >=1 barrier after last read. vmcnt(6) once/K-tile.
__global__ __launch_bounds__(512, 2) void gemm256(
    const u16* __restrict__ A, const u16* __restrict__ Bq,
    const float* __restrict__ bias, const float* __restrict__ alpha_f,
    float* __restrict__ C) {
  __shared__ __align__(16) u16 Alds[2][2][128 * 64];  // [parity][half][r*64+k]
  __shared__ __align__(16) u16 Blds[2][2][128 * 64];

  const int t = threadIdx.x;
  const int wv = t >> 6, l = t & 63;
  const int wr = wv >> 2, wc = wv & 3;  // 2M x 4N wave grid
  const int lr = l & 15, lk = l >> 4;

  // XCD-bijective swizzle (2048 % 8 == 0) + 8(tm) x 64(tn) supertiles
  const int bid = blockIdx.x;
  const int wg = (bid & 7) * 256 + (bid >> 3);
  const int grp = wg >> 9, rem = wg & 511;
  const int tm = grp * 8 + (rem & 7);  // 0..31
  const int tn = rem >> 3;             // 0..63

  const u16* Ag = A + (size_t)tm * 256 * K_DIM;
  const u16* Bg = Bq + (size_t)tn * 256 * K_DIM;

  // staging source offsets (pre-swizzled global source, linear LDS dest)
  const int q0 = t, q1 = 512 + t;
  const int r0 = q0 >> 3, c0 = (q0 & 7) ^ (r0 & 7);
  const int r1 = q1 >> 3, c1 = (q1 & 7) ^ (r1 & 7);
  const size_t so0 = (size_t)r0 * K_DIM + c0 * 8;
  const size_t so1 = (size_t)r1 * K_DIM + c1 * 8;
  const int do0 = (wv * 64) * 8;          // u16 units (wave-uniform dest base)
  const int do1 = (512 + wv * 64) * 8;

  // Swizzled frag read bases (u16 units). For frag row r = sub*16 + lr:
  // r&7 == lr&7, so offset = sub*1024 + fb[ks];  sub*1024 folds to imm offset.
  const int fb0 = lr * 64 + ((lk ^ (lr & 7)) * 8);
  const int fb1 = lr * 64 + (((4 + lk) ^ (lr & 7)) * 8);
#define LDF(ptr, sub, ks) (*(const bf16x8*)((ptr) + (sub) * 1024 + ((ks) ? fb1 : fb0)))

  f32x4 acc[8][4];
#pragma unroll
  for (int mi = 0; mi < 8; ++mi)
#pragma unroll
    for (int ni = 0; ni < 4; ++ni)
      acc[mi][ni] = (f32x4){0.f, 0.f, 0.f, 0.f};

  // stage one half-tile H (2 x global_load_lds per wave); no-op past last tile
  auto stage = [&](int H) {
    int g = H >> 2;
    if (g < NT) {
      int sub = H & 3;  // 0:B0 1:B1 2:A0 3:A1
      const u16* src;
      u16* dst;
      if (sub < 2) { src = Bg + (size_t)sub * (128 * K_DIM); dst = &Blds[g & 1][sub][0]; }
      else         { src = Ag + (size_t)(sub - 2) * (128 * K_DIM); dst = &Alds[g & 1][sub - 2][0]; }
      src += g * 64;
      gload16(src + so0, dst + do0);
      gload16(src + so1, dst + do1);
    }
  };

  // one K-tile = 4 phases; par is a compile-time constant at each expansion
#define K_TILE(kt, par)                                                        \
  {                                                                            \
    const u16* Ar = &Alds[par][wr][0];                                         \
    const u16* Br = &Blds[par][wc >> 1][0] + (wc & 1) * 4096;                  \
    bf16x8 bv[4][2], aA[2][2], aB[2][2], aC[2][2], aD[2][2];                   \
    /* ---- P0: read B(8)+A01(4); stage A1(kt+1); MFMA mi01 ---- */            \
    _Pragma("unroll") for (int ni = 0; ni < 4; ++ni) {                         \
      bv[ni][0] = LDF(Br, ni, 0); bv[ni][1] = LDF(Br, ni, 1);                  \
    }                                                                          \
    _Pragma("unroll") for (int m = 0; m < 2; ++m) {                            \
      aA[m][0] = LDF(Ar, m, 0); aA[m][1] = LDF(Ar, m, 1);                      \
    }                                                                          \
    stage(4 * (kt) + 7);                                                       \
    __builtin_amdgcn_s_barrier();                                              \
    asm volatile("s_waitcnt lgkmcnt(0)" ::: "memory");                         \
    __builtin_amdgcn_s_setprio(1);                                             \
    _Pragma("unroll") for (int ks = 0; ks < 2; ++ks)                           \
      _Pragma("unroll") for (int m = 0; m < 2; ++m)                            \
        _Pragma("unroll") for (int ni = 0; ni < 4; ++ni)                       \
          acc[m][ni] = MFMA(aA[m][ks], bv[ni][ks], acc[m][ni]);                \
    __builtin_amdgcn_s_setprio(0);                                             \
    __builtin_amdgcn_s_barrier();                                              \
    /* ---- P1: read A23,A45(8); stage B0(kt+2); MFMA mi23 ---- */             \
    _Pragma("unroll") for (int m = 0; m < 2; ++m) {                            \
      aB[m][0] = LDF(Ar, 2 + m, 0); aB[m][1] = LDF(Ar, 2 + m, 1);              \
      aC[m][0] = LDF(Ar, 4 + m, 0); aC[m][1] = LDF(Ar, 4 + m, 1);              \
    }                                                                          \
    stage(4 * (kt) + 8);                                                       \
    __builtin_amdgcn_s_barrier();                                              \
    asm volatile("s_waitcnt lgkmcnt(0)" ::: "memory");                         \
    __builtin_amdgcn_s_setprio(1);                                             \
    _Pragma("unroll") for (int ks = 0; ks < 2; ++ks)                           \
      _Pragma("unroll") for (int m = 0; m < 2; ++m)                            \
        _Pragma("unroll") for (int ni = 0; ni < 4; ++ni)                       \
          acc[2 + m][ni] = MFMA(aB[m][ks], bv[ni][ks], acc[2 + m][ni]);        \
    __builtin_amdgcn_s_setprio(0);                                             \
    __builtin_amdgcn_s_barrier();                                              \
    /* ---- P2: read A67(4); stage B1(kt+2); MFMA mi45 ---- */                 \
    _Pragma("unroll") for (int m = 0; m < 2; ++m) {                            \
      aD[m][0] = LDF(Ar, 6 + m, 0); aD[m][1] = LDF(Ar, 6 + m, 1);              \
    }                                                                          \
    stage(4 * (kt) + 9);                                                       \
    __builtin_amdgcn_s_barrier();                                              \
    asm volatile("s_waitcnt lgkmcnt(0)" ::: "memory");                         \
    __builtin_amdgcn_s_setprio(1);                                             \
    _Pragma("unroll") for (int ks = 0; ks < 2; ++ks)                           \
      _Pragma("unroll") for (int m = 0; m < 2; ++m)                            \
        _Pragma("unroll") for (int ni = 0; ni < 4; ++ni)                       \
          acc[4 + m][ni] = MFMA(aC[m][ks], bv[ni][ks], acc[4 + m][ni]);        \
    __builtin_amdgcn_s_setprio(0);                                             \
    __builtin_amdgcn_s_barrier();                                              \
    /* ---- P3: stage A0(kt+2); MFMA mi67 (aD drained in P2); vmcnt ---- */    \
    stage(4 * (kt) + 10);                                                      \
    __builtin_amdgcn_s_barrier();                                              \
    __builtin_amdgcn_s_setprio(1);                                             \
    _Pragma("unroll") for (int ks = 0; ks < 2; ++ks)                           \
      _Pragma("unroll") for (int m = 0; m < 2; ++m)                            \
        _Pragma("unroll") for (int ni = 0; ni < 4; ++ni)                       \
          acc[6 + m][ni] = MFMA(aD[m][ks], bv[ni][ks], acc[6 + m][ni]);        \
    __builtin_amdgcn_s_setprio(0);                                             \
    if ((kt) < NT - 2) asm volatile("s_waitcnt vmcnt(6)" ::: "memory");        \
    else               asm volatile("s_waitcnt vmcnt(0)" ::: "memory");        \
    __builtin_amdgcn_s_barrier();                                              \
  }

  // prologue: issue halves 0..6 (tile0 complete + 3 halves of tile1 in flight)
#pragma unroll
  for (int H = 0; H < 7; ++H) stage(H);
  asm volatile("s_waitcnt vmcnt(6)" ::: "memory");
  __builtin_amdgcn_s_barrier();

  for (int kt2 = 0; kt2 < NT; kt2 += 2) {
    K_TILE(kt2, 0);
    K_TILE(kt2 + 1, 1);
  }
#undef K_TILE
#undef LDF

  // epilogue: y = alpha*acc + bias.  C/D: col=l&15, row=4*(l>>4)+j (m89-verified)
  const float alpha = alpha_f[0];
#pragma unroll
  for (int ni = 0; ni < 4; ++ni) {
    const int col = tn * 256 + wc * 64 + ni * 16 + lr;
    const float bs = bias[col];
#pragma unroll
    for (int mi = 0; mi < 8; ++mi) {
      const int row = tm * 256 + wr * 128 + mi * 16 + lk * 4;
      float* Cp = C + (size_t)row * N_DIM + col;
#pragma unroll
      for (int j = 0; j < 4; ++j)
        Cp[(size_t)j * N_DIM] = alpha * acc[mi][ni][j] + bs;
    }
  }
}

extern "C" void kernel_launch(void* const* d_in, const int* in_sizes, int n_in,
                              void* d_out, int out_size, void* d_ws, size_t ws_size,
                              hipStream_t stream) {
  const float* x = (const float*)d_in[0];
  const float* w = (const float*)d_in[1];
  const float* bias = (const float*)d_in[2];
  float* out = (float*)d_out;

  char* ws = (char*)d_ws;
  double* alpha_d = (double*)ws;
  float* alpha_f = (float*)(ws + 8);
  double* partials = (double*)(ws + 16);
  u16* xb = (u16*)(ws + 65536);                 // 64 MiB (M*K bf16)
  u16* qb = (u16*)(ws + 65536 + 67108864ULL);   // 128 MiB (N*K bf16)

  reduce_abs1<<<4096, 256, 0, stream>>>(w, partials);
  reduce_abs2<<<1, 256, 0, stream>>>(partials, alpha_d, alpha_f);
  quant_w<<<32768, 256, 0, stream>>>(w, alpha_d, qb);
  conv_x<<<16384, 256, 0, stream>>>(x, xb);
  gemm256<<<2048, 512, 0, stream>>>(xb, qb, bias, alpha_f, out);
}

// Round 4
// 1193.884 us; speedup vs baseline: 1.4068x; 1.0428x over previous
//
#include <hip/hip_runtime.h>

// y = alpha*(x @ Q^T) + bias; alpha = mean|W|; Q = clip(round(W/alpha),-1,1)
// x:(2,4096,4096) f32, W:(16384,4096) f32, bias:(16384) f32, out f32.
#define M_DIM 8192
#define N_DIM 16384
#define K_DIM 4096
#define NT 64  // K_DIM / 64

typedef unsigned short u16;
typedef unsigned int u32;
typedef __attribute__((ext_vector_type(8))) short bf16x8;
typedef __attribute__((ext_vector_type(8))) unsigned short u16x8;
typedef __attribute__((ext_vector_type(4))) float f32x4;

#define MFMA(a, b, c) __builtin_amdgcn_mfma_f32_16x16x32_bf16(a, b, c, 0, 0, 0)

__device__ __forceinline__ void gload16(const u16* g, u16* l) {
  __builtin_amdgcn_global_load_lds((const __attribute__((address_space(1))) void*)g,
                                   (__attribute__((address_space(3))) void*)l, 16, 0, 0);
}

// ---------------- alpha = mean(|W|), f64 two-pass reduction ----------------
__global__ void reduce_abs1(const float* __restrict__ w, double* __restrict__ partials) {
  const float4* w4 = (const float4*)w;
  size_t base = (size_t)blockIdx.x * 4096 + threadIdx.x;
  double s = 0.0;
#pragma unroll
  for (int i = 0; i < 16; ++i) {
    float4 v = w4[base + (size_t)i * 256];
    s += (double)fabsf(v.x); s += (double)fabsf(v.y);
    s += (double)fabsf(v.z); s += (double)fabsf(v.w);
  }
#pragma unroll
  for (int off = 32; off > 0; off >>= 1) s += __shfl_down(s, off, 64);
  __shared__ double red[4];
  int wv = threadIdx.x >> 6, lane = threadIdx.x & 63;
  if (lane == 0) red[wv] = s;
  __syncthreads();
  if (threadIdx.x == 0) partials[blockIdx.x] = (red[0] + red[1]) + (red[2] + red[3]);
}

__global__ void reduce_abs2(const double* __restrict__ partials,
                            double* __restrict__ alpha_d, float* __restrict__ alpha_f) {
  double s = 0.0;
  for (int i = threadIdx.x; i < 4096; i += 256) s += partials[i];
#pragma unroll
  for (int off = 32; off > 0; off >>= 1) s += __shfl_down(s, off, 64);
  __shared__ double red[4];
  int wv = threadIdx.x >> 6, lane = threadIdx.x & 63;
  if (lane == 0) red[wv] = s;
  __syncthreads();
  if (threadIdx.x == 0) {
    double total = (red[0] + red[1]) + (red[2] + red[3]);
    double a = total / (double)((long long)N_DIM * (long long)K_DIM);
    alpha_d[0] = a;
    alpha_f[0] = (float)a;
  }
}

// ---------------- W -> ternary Q stored as bf16 (+1/0/-1 exact) ----------------
__global__ void quant_w(const float* __restrict__ w, const double* __restrict__ alpha_d,
                        u16* __restrict__ q) {
  double inv = 1.0 / alpha_d[0];
  size_t i8 = (size_t)blockIdx.x * 256 + threadIdx.x;
  const float4* w4 = (const float4*)w;
  float4 v0 = w4[i8 * 2], v1 = w4[i8 * 2 + 1];
  float vv[8] = {v0.x, v0.y, v0.z, v0.w, v1.x, v1.y, v1.z, v1.w};
  u16x8 o;
#pragma unroll
  for (int j = 0; j < 8; ++j) {
    double r = rint((double)vv[j] * inv);
    u16 enc = 0;
    if (r >= 1.0) enc = 0x3F80u;
    else if (r <= -1.0) enc = 0xBF80u;
    o[j] = enc;
  }
  *((u16x8*)q + i8) = o;
}

// ---------------- x fp32 -> bf16 (RNE) ----------------
__global__ void conv_x(const float* __restrict__ x, u16* __restrict__ xb) {
  size_t i8 = (size_t)blockIdx.x * 256 + threadIdx.x;
  const float4* x4 = (const float4*)x;
  float4 v0 = x4[i8 * 2], v1 = x4[i8 * 2 + 1];
  float vv[8] = {v0.x, v0.y, v0.z, v0.w, v1.x, v1.y, v1.z, v1.w};
  u16x8 o;
#pragma unroll
  for (int j = 0; j < 8; ++j) {
    u32 u = __float_as_uint(vv[j]);
    u += 0x7FFFu + ((u >> 16) & 1u);
    o[j] = (u16)(u >> 16);
  }
  *((u16x8*)xb + i8) = o;
}

// ------- 256x256-tile bf16 GEMM, 4-region pipelined schedule (T2+T4+T5) -------
// 512 threads = 8 waves (2M x 4N); per-wave 128x64 output = acc[8][4] f32x4.
// LDS: 2 tile-buffers x {A 256x64, B 256x64} bf16 = 128 KiB.
// Region P: [issue ds_reads for P+1 (same tile); stage; sched_barrier;
//            MFMA(P) (operands read in P-1, compiler counted-wait);
//            lgkmcnt(0) drain (free, post-MFMA); barrier]
// -> LDS pipe serves P+1's reads WHILE MFMA(P) runs (no block-wide alternation).
// The post-MFMA lgkmcnt(0)+barrier guarantees every stage lands after all
// in-flight reads of the half it overwrites. vmcnt(6) once per K-tile.
__global__ __launch_bounds__(512, 2) void gemm256(
    const u16* __restrict__ A, const u16* __restrict__ Bq,
    const float* __restrict__ bias, const float* __restrict__ alpha_f,
    float* __restrict__ C) {
  __shared__ __align__(16) u16 Alds[2][2][128 * 64];  // [parity][half][r*64+k]
  __shared__ __align__(16) u16 Blds[2][2][128 * 64];

  const int t = threadIdx.x;
  const int wv = t >> 6, l = t & 63;
  const int wr = wv >> 2, wc = wv & 3;  // 2M x 4N wave grid
  const int lr = l & 15, lk = l >> 4;

  // XCD-bijective swizzle (2048 % 8 == 0) + 8(tm) x 64(tn) supertiles
  const int bid = blockIdx.x;
  const int wg = (bid & 7) * 256 + (bid >> 3);
  const int grp = wg >> 9, rem = wg & 511;
  const int tm = grp * 8 + (rem & 7);  // 0..31
  const int tn = rem >> 3;             // 0..63

  const u16* Ag = A + (size_t)tm * 256 * K_DIM;
  const u16* Bg = Bq + (size_t)tn * 256 * K_DIM;

  // staging source offsets (pre-swizzled global source, linear LDS dest)
  const int q0 = t, q1 = 512 + t;
  const int r0 = q0 >> 3, c0 = (q0 & 7) ^ (r0 & 7);
  const int r1 = q1 >> 3, c1 = (q1 & 7) ^ (r1 & 7);
  const size_t so0 = (size_t)r0 * K_DIM + c0 * 8;
  const size_t so1 = (size_t)r1 * K_DIM + c1 * 8;
  const int do0 = (wv * 64) * 8;          // u16 units (wave-uniform dest base)
  const int do1 = (512 + wv * 64) * 8;

  // Swizzled frag read bases (u16 units). For frag row r = sub*16 + lr:
  // r&7 == lr&7, so offset = sub*1024 + fb[ks];  sub*1024 folds to imm offset.
  const int fb0 = lr * 64 + ((lk ^ (lr & 7)) * 8);
  const int fb1 = lr * 64 + (((4 + lk) ^ (lr & 7)) * 8);
#define LDF(ptr, sub, ks) (*(const bf16x8*)((ptr) + (sub) * 1024 + ((ks) ? fb1 : fb0)))

  f32x4 acc[8][4];
#pragma unroll
  for (int mi = 0; mi < 8; ++mi)
#pragma unroll
    for (int ni = 0; ni < 4; ++ni)
      acc[mi][ni] = (f32x4){0.f, 0.f, 0.f, 0.f};

  // stage one half-tile H (2 x global_load_lds per wave); no-op past last tile
  auto stage = [&](int H) {
    int g = H >> 2;
    if (g < NT) {
      int sub = H & 3;  // 0:B0 1:B1 2:A0 3:A1
      const u16* src;
      u16* dst;
      if (sub < 2) { src = Bg + (size_t)sub * (128 * K_DIM); dst = &Blds[g & 1][sub][0]; }
      else         { src = Ag + (size_t)(sub - 2) * (128 * K_DIM); dst = &Alds[g & 1][sub - 2][0]; }
      src += g * 64;
      gload16(src + so0, dst + do0);
      gload16(src + so1, dst + do1);
    }
  };

#define SBAR() __builtin_amdgcn_sched_barrier(0)
#define DRAIN_BAR()                                       \
  asm volatile("s_waitcnt lgkmcnt(0)" ::: "memory");      \
  __builtin_amdgcn_s_barrier()

  // one K-tile = 4 regions; par is a compile-time constant at each expansion
#define K_TILE(kt, par)                                                        \
  {                                                                            \
    const u16* Ar = &Alds[par][wr][0];                                         \
    const u16* Br = &Blds[par][wc >> 1][0] + (wc & 1) * 4096;                  \
    bf16x8 bv[4][2], aA[2][2], aB[2][2], aC[2][2], aD[2][2];                   \
    /* -- R0: burst reads B(8)+A01(4); hoist A23(4); stage A1(kt+1) -- */      \
    _Pragma("unroll") for (int ni = 0; ni < 4; ++ni) {                         \
      bv[ni][0] = LDF(Br, ni, 0); bv[ni][1] = LDF(Br, ni, 1);                  \
    }                                                                          \
    _Pragma("unroll") for (int m = 0; m < 2; ++m) {                            \
      aA[m][0] = LDF(Ar, m, 0); aA[m][1] = LDF(Ar, m, 1);                      \
      aB[m][0] = LDF(Ar, 2 + m, 0); aB[m][1] = LDF(Ar, 2 + m, 1);              \
    }                                                                          \
    stage(4 * (kt) + 7);                                                       \
    SBAR();                                                                    \
    __builtin_amdgcn_s_setprio(1);                                             \
    _Pragma("unroll") for (int ks = 0; ks < 2; ++ks)                           \
      _Pragma("unroll") for (int m = 0; m < 2; ++m)                            \
        _Pragma("unroll") for (int ni = 0; ni < 4; ++ni)                       \
          acc[m][ni] = MFMA(aA[m][ks], bv[ni][ks], acc[m][ni]);                \
    __builtin_amdgcn_s_setprio(0);                                             \
    SBAR();                                                                    \
    DRAIN_BAR();                                                               \
    /* -- R1: hoist A45(4); stage B0(kt+2); MFMA mi23 -- */                    \
    _Pragma("unroll") for (int m = 0; m < 2; ++m) {                            \
      aC[m][0] = LDF(Ar, 4 + m, 0); aC[m][1] = LDF(Ar, 4 + m, 1);              \
    }                                                                          \
    stage(4 * (kt) + 8);                                                       \
    SBAR();                                                                    \
    __builtin_amdgcn_s_setprio(1);                                             \
    _Pragma("unroll") for (int ks = 0; ks < 2; ++ks)                           \
      _Pragma("unroll") for (int m = 0; m < 2; ++m)                            \
        _Pragma("unroll") for (int ni = 0; ni < 4; ++ni)                       \
          acc[2 + m][ni] = MFMA(aB[m][ks], bv[ni][ks], acc[2 + m][ni]);        \
    __builtin_amdgcn_s_setprio(0);                                             \
    SBAR();                                                                    \
    DRAIN_BAR();                                                               \
    /* -- R2: hoist A67(4); stage B1(kt+2); MFMA mi45 -- */                    \
    _Pragma("unroll") for (int m = 0; m < 2; ++m) {                            \
      aD[m][0] = LDF(Ar, 6 + m, 0); aD[m][1] = LDF(Ar, 6 + m, 1);              \
    }                                                                          \
    stage(4 * (kt) + 9);                                                       \
    SBAR();                                                                    \
    __builtin_amdgcn_s_setprio(1);                                             \
    _Pragma("unroll") for (int ks = 0; ks < 2; ++ks)                           \
      _Pragma("unroll") for (int m = 0; m < 2; ++m)                            \
        _Pragma("unroll") for (int ni = 0; ni < 4; ++ni)                       \
          acc[4 + m][ni] = MFMA(aC[m][ks], bv[ni][ks], acc[4 + m][ni]);        \
    __builtin_amdgcn_s_setprio(0);                                             \
    SBAR();                                                                    \
    DRAIN_BAR();                                                               \
    /* -- R3: stage A0(kt+2); MFMA mi67; vmcnt; barrier -- */                  \
    stage(4 * (kt) + 10);                                                      \
    SBAR();                                                                    \
    __builtin_amdgcn_s_setprio(1);                                             \
    _Pragma("unroll") for (int ks = 0; ks < 2; ++ks)                           \
      _Pragma("unroll") for (int m = 0; m < 2; ++m)                            \
        _Pragma("unroll") for (int ni = 0; ni < 4; ++ni)                       \
          acc[6 + m][ni] = MFMA(aD[m][ks], bv[ni][ks], acc[6 + m][ni]);        \
    __builtin_amdgcn_s_setprio(0);                                             \
    SBAR();                                                                    \
    if ((kt) < NT - 2) asm volatile("s_waitcnt vmcnt(6)" ::: "memory");        \
    else               asm volatile("s_waitcnt vmcnt(0)" ::: "memory");        \
    DRAIN_BAR();                                                               \
  }

  // prologue: issue halves 0..6 (tile0 complete + 3 halves of tile1 in flight)
#pragma unroll
  for (int H = 0; H < 7; ++H) stage(H);
  asm volatile("s_waitcnt vmcnt(6)" ::: "memory");
  __builtin_amdgcn_s_barrier();

  for (int kt2 = 0; kt2 < NT; kt2 += 2) {
    K_TILE(kt2, 0);
    K_TILE(kt2 + 1, 1);
  }
#undef K_TILE
#undef LDF

  // epilogue: y = alpha*acc + bias.  C/D: col=l&15, row=4*(l>>4)+j (m89-verified)
  const float alpha = alpha_f[0];
#pragma unroll
  for (int ni = 0; ni < 4; ++ni) {
    const int col = tn * 256 + wc * 64 + ni * 16 + lr;
    const float bs = bias[col];
#pragma unroll
    for (int mi = 0; mi < 8; ++mi) {
      const int row = tm * 256 + wr * 128 + mi * 16 + lk * 4;
      float* Cp = C + (size_t)row * N_DIM + col;
#pragma unroll
      for (int j = 0; j < 4; ++j)
        Cp[(size_t)j * N_DIM] = alpha * acc[mi][ni][j] + bs;
    }
  }
}

extern "C" void kernel_launch(void* const* d_in, const int* in_sizes, int n_in,
                              void* d_out, int out_size, void* d_ws, size_t ws_size,
                              hipStream_t stream) {
  const float* x = (const float*)d_in[0];
  const float* w = (const float*)d_in[1];
  const float* bias = (const float*)d_in[2];
  float* out = (float*)d_out;

  char* ws = (char*)d_ws;
  double* alpha_d = (double*)ws;
  float* alpha_f = (float*)(ws + 8);
  double* partials = (double*)(ws + 16);
  u16* xb = (u16*)(ws + 65536);                 // 64 MiB (M*K bf16)
  u16* qb = (u16*)(ws + 65536 + 67108864ULL);   // 128 MiB (N*K bf16)

  reduce_abs1<<<4096, 256, 0, stream>>>(w, partials);
  reduce_abs2<<<1, 256, 0, stream>>>(partials, alpha_d, alpha_f);
  quant_w<<<32768, 256, 0, stream>>>(w, alpha_d, qb);
  conv_x<<<16384, 256, 0, stream>>>(x, xb);
  gemm256<<<2048, 512, 0, stream>>>(xb, qb, bias, alpha_f, out);
}

// Round 5
// 1178.242 us; speedup vs baseline: 1.4255x; 1.0133x over previous
//
#include <hip/hip_runtime.h>

// y = alpha*(x @ Q^T) + bias; alpha = mean|W|; Q = clip(round(W/alpha),-1,1)
// x:(2,4096,4096) f32, W:(16384,4096) f32, bias:(16384) f32, out f32.
#define M_DIM 8192
#define N_DIM 16384
#define K_DIM 4096
#define NT 64  // K_DIM / 64

typedef unsigned short u16;
typedef unsigned int u32;
typedef __attribute__((ext_vector_type(8))) short bf16x8;
typedef __attribute__((ext_vector_type(8))) unsigned short u16x8;
typedef __attribute__((ext_vector_type(4))) float f32x4;

#define MFMA(a, b, c) __builtin_amdgcn_mfma_f32_16x16x32_bf16(a, b, c, 0, 0, 0)

__device__ __forceinline__ void gload16(const u16* g, u16* l) {
  __builtin_amdgcn_global_load_lds((const __attribute__((address_space(1))) void*)g,
                                   (__attribute__((address_space(3))) void*)l, 16, 0, 0);
}

// ---------------- alpha = mean(|W|), f64 two-pass reduction ----------------
__global__ void reduce_abs1(const float* __restrict__ w, double* __restrict__ partials) {
  const float4* w4 = (const float4*)w;
  size_t base = (size_t)blockIdx.x * 4096 + threadIdx.x;
  double s = 0.0;
#pragma unroll
  for (int i = 0; i < 16; ++i) {
    float4 v = w4[base + (size_t)i * 256];
    s += (double)fabsf(v.x); s += (double)fabsf(v.y);
    s += (double)fabsf(v.z); s += (double)fabsf(v.w);
  }
#pragma unroll
  for (int off = 32; off > 0; off >>= 1) s += __shfl_down(s, off, 64);
  __shared__ double red[4];
  int wv = threadIdx.x >> 6, lane = threadIdx.x & 63;
  if (lane == 0) red[wv] = s;
  __syncthreads();
  if (threadIdx.x == 0) partials[blockIdx.x] = (red[0] + red[1]) + (red[2] + red[3]);
}

__global__ void reduce_abs2(const double* __restrict__ partials,
                            double* __restrict__ alpha_d, float* __restrict__ alpha_f) {
  double s = 0.0;
  for (int i = threadIdx.x; i < 4096; i += 256) s += partials[i];
#pragma unroll
  for (int off = 32; off > 0; off >>= 1) s += __shfl_down(s, off, 64);
  __shared__ double red[4];
  int wv = threadIdx.x >> 6, lane = threadIdx.x & 63;
  if (lane == 0) red[wv] = s;
  __syncthreads();
  if (threadIdx.x == 0) {
    double total = (red[0] + red[1]) + (red[2] + red[3]);
    double a = total / (double)((long long)N_DIM * (long long)K_DIM);
    alpha_d[0] = a;
    alpha_f[0] = (float)a;
  }
}

// ---------------- W -> ternary Q stored as bf16 (+1/0/-1 exact) ----------------
__global__ void quant_w(const float* __restrict__ w, const double* __restrict__ alpha_d,
                        u16* __restrict__ q) {
  double inv = 1.0 / alpha_d[0];
  size_t i8 = (size_t)blockIdx.x * 256 + threadIdx.x;
  const float4* w4 = (const float4*)w;
  float4 v0 = w4[i8 * 2], v1 = w4[i8 * 2 + 1];
  float vv[8] = {v0.x, v0.y, v0.z, v0.w, v1.x, v1.y, v1.z, v1.w};
  u16x8 o;
#pragma unroll
  for (int j = 0; j < 8; ++j) {
    double r = rint((double)vv[j] * inv);
    u16 enc = 0;
    if (r >= 1.0) enc = 0x3F80u;
    else if (r <= -1.0) enc = 0xBF80u;
    o[j] = enc;
  }
  *((u16x8*)q + i8) = o;
}

// ---------------- x fp32 -> bf16 (RNE) ----------------
__global__ void conv_x(const float* __restrict__ x, u16* __restrict__ xb) {
  size_t i8 = (size_t)blockIdx.x * 256 + threadIdx.x;
  const float4* x4 = (const float4*)x;
  float4 v0 = x4[i8 * 2], v1 = x4[i8 * 2 + 1];
  float vv[8] = {v0.x, v0.y, v0.z, v0.w, v1.x, v1.y, v1.z, v1.w};
  u16x8 o;
#pragma unroll
  for (int j = 0; j < 8; ++j) {
    u32 u = __float_as_uint(vv[j]);
    u += 0x7FFFu + ((u >> 16) & 1u);
    o[j] = (u16)(u >> 16);
  }
  *((u16x8*)xb + i8) = o;
}

// ------- 256x256-tile bf16 GEMM, faithful m201 8-phase template -------
// 512 threads = 8 waves (2M x 4N); per-wave 128x64 output = acc[8][4] f32x4.
// LDS: 2 tile-buffers x {A 256x64, B 256x64} bf16 = 128 KiB.
// Per phase: {ds_reads; stage; [lgkmcnt(8) if 12 reads]; barrier; lgkmcnt(0);
//             setprio(1); 16 MFMA (one C-quadrant); setprio(0); barrier}.
// Quadrants: P0 mi0-3 x ni0-1 (reads A0-3 + B0-1), P1 mi0-3 x ni2-3 (reads
// B2-3), P2 mi4-7 x ni0-1 (reads A4-7), P3 mi4-7 x ni2-3 (no reads).
// The 2-barrier cadence lets waves skew: early lgkm-finishers start MFMA while
// SIMD-partner waves still drain -> wave-level MFMA||LDS overlap (m201/m218).
// vmcnt(6) once per K-tile at P3 (3 half-tiles in flight); vmcnt(0) last 2.
__global__ __launch_bounds__(512, 2) void gemm256(
    const u16* __restrict__ A, const u16* __restrict__ Bq,
    const float* __restrict__ bias, const float* __restrict__ alpha_f,
    float* __restrict__ C) {
  __shared__ __align__(16) u16 Alds[2][2][128 * 64];  // [parity][half][r*64+k]
  __shared__ __align__(16) u16 Blds[2][2][128 * 64];

  const int t = threadIdx.x;
  const int wv = t >> 6, l = t & 63;
  const int wr = wv >> 2, wc = wv & 3;  // 2M x 4N wave grid
  const int lr = l & 15, lk = l >> 4;

  // XCD-bijective swizzle (2048 % 8 == 0) + 8(tm) x 64(tn) supertiles
  const int bid = blockIdx.x;
  const int wg = (bid & 7) * 256 + (bid >> 3);
  const int grp = wg >> 9, rem = wg & 511;
  const int tm = grp * 8 + (rem & 7);  // 0..31
  const int tn = rem >> 3;             // 0..63

  const u16* Ag = A + (size_t)tm * 256 * K_DIM;
  const u16* Bg = Bq + (size_t)tn * 256 * K_DIM;

  // staging source offsets (pre-swizzled global source, linear LDS dest)
  const int q0 = t, q1 = 512 + t;
  const int r0 = q0 >> 3, c0 = (q0 & 7) ^ (r0 & 7);
  const int r1 = q1 >> 3, c1 = (q1 & 7) ^ (r1 & 7);
  const size_t so0 = (size_t)r0 * K_DIM + c0 * 8;
  const size_t so1 = (size_t)r1 * K_DIM + c1 * 8;
  const int do0 = (wv * 64) * 8;          // u16 units (wave-uniform dest base)
  const int do1 = (512 + wv * 64) * 8;

  // Swizzled frag read bases (u16 units). For frag row r = sub*16 + lr:
  // r&7 == lr&7, so offset = sub*1024 + fb[ks];  sub*1024 folds to imm offset.
  const int fb0 = lr * 64 + ((lk ^ (lr & 7)) * 8);
  const int fb1 = lr * 64 + (((4 + lk) ^ (lr & 7)) * 8);
#define LDF(ptr, sub, ks) (*(const bf16x8*)((ptr) + (sub) * 1024 + ((ks) ? fb1 : fb0)))

  f32x4 acc[8][4];
#pragma unroll
  for (int mi = 0; mi < 8; ++mi)
#pragma unroll
    for (int ni = 0; ni < 4; ++ni)
      acc[mi][ni] = (f32x4){0.f, 0.f, 0.f, 0.f};

  // stage one half-tile H (2 x global_load_lds per wave); no-op past last tile
  auto stage = [&](int H) {
    int g = H >> 2;
    if (g < NT) {
      int sub = H & 3;  // 0:B0 1:B1 2:A0 3:A1
      const u16* src;
      u16* dst;
      if (sub < 2) { src = Bg + (size_t)sub * (128 * K_DIM); dst = &Blds[g & 1][sub][0]; }
      else         { src = Ag + (size_t)(sub - 2) * (128 * K_DIM); dst = &Alds[g & 1][sub - 2][0]; }
      src += g * 64;
      gload16(src + so0, dst + do0);
      gload16(src + so1, dst + do1);
    }
  };

#define WAIT0()                                          \
  asm volatile("s_waitcnt lgkmcnt(0)" ::: "memory");     \
  __builtin_amdgcn_sched_barrier(0)

  // one K-tile = 4 phases; par is a compile-time constant at each expansion
#define K_TILE(kt, par)                                                        \
  {                                                                            \
    const u16* Ar = &Alds[par][wr][0];                                         \
    const u16* Br = &Blds[par][wc >> 1][0] + (wc & 1) * 4096;                  \
    bf16x8 bv[4][2], aA[4][2], aB[4][2];                                       \
    /* -- P0: read A0-3(8)+B0-1(4); stage A1(kt+1); MFMA mi0-3 x ni0-1 -- */   \
    _Pragma("unroll") for (int m = 0; m < 4; ++m) {                            \
      aA[m][0] = LDF(Ar, m, 0); aA[m][1] = LDF(Ar, m, 1);                      \
    }                                                                          \
    _Pragma("unroll") for (int ni = 0; ni < 2; ++ni) {                         \
      bv[ni][0] = LDF(Br, ni, 0); bv[ni][1] = LDF(Br, ni, 1);                  \
    }                                                                          \
    stage(4 * (kt) + 7);                                                       \
    asm volatile("s_waitcnt lgkmcnt(8)" ::: "memory");                         \
    __builtin_amdgcn_s_barrier();                                              \
    WAIT0();                                                                   \
    __builtin_amdgcn_s_setprio(1);                                             \
    _Pragma("unroll") for (int ks = 0; ks < 2; ++ks)                           \
      _Pragma("unroll") for (int m = 0; m < 4; ++m)                            \
        _Pragma("unroll") for (int ni = 0; ni < 2; ++ni)                       \
          acc[m][ni] = MFMA(aA[m][ks], bv[ni][ks], acc[m][ni]);                \
    __builtin_amdgcn_s_setprio(0);                                             \
    __builtin_amdgcn_s_barrier();                                              \
    /* -- P1: read B2-3(4); stage B0(kt+2); MFMA mi0-3 x ni2-3 -- */           \
    _Pragma("unroll") for (int ni = 2; ni < 4; ++ni) {                         \
      bv[ni][0] = LDF(Br, ni, 0); bv[ni][1] = LDF(Br, ni, 1);                  \
    }                                                                          \
    stage(4 * (kt) + 8);                                                       \
    __builtin_amdgcn_s_barrier();                                              \
    WAIT0();                                                                   \
    __builtin_amdgcn_s_setprio(1);                                             \
    _Pragma("unroll") for (int ks = 0; ks < 2; ++ks)                           \
      _Pragma("unroll") for (int m = 0; m < 4; ++m)                            \
        _Pragma("unroll") for (int ni = 2; ni < 4; ++ni)                       \
          acc[m][ni] = MFMA(aA[m][ks], bv[ni][ks], acc[m][ni]);                \
    __builtin_amdgcn_s_setprio(0);                                             \
    __builtin_amdgcn_s_barrier();                                              \
    /* -- P2: read A4-7(8); stage B1(kt+2); MFMA mi4-7 x ni0-1 -- */           \
    _Pragma("unroll") for (int m = 0; m < 4; ++m) {                            \
      aB[m][0] = LDF(Ar, 4 + m, 0); aB[m][1] = LDF(Ar, 4 + m, 1);              \
    }                                                                          \
    stage(4 * (kt) + 9);                                                       \
    __builtin_amdgcn_s_barrier();                                              \
    WAIT0();                                                                   \
    __builtin_amdgcn_s_setprio(1);                                             \
    _Pragma("unroll") for (int ks = 0; ks < 2; ++ks)                           \
      _Pragma("unroll") for (int m = 0; m < 4; ++m)                            \
        _Pragma("unroll") for (int ni = 0; ni < 2; ++ni)                       \
          acc[4 + m][ni] = MFMA(aB[m][ks], bv[ni][ks], acc[4 + m][ni]);        \
    __builtin_amdgcn_s_setprio(0);                                             \
    __builtin_amdgcn_s_barrier();                                              \
    /* -- P3: no reads; stage A0(kt+2); MFMA mi4-7 x ni2-3; vmcnt -- */        \
    stage(4 * (kt) + 10);                                                      \
    __builtin_amdgcn_s_barrier();                                              \
    __builtin_amdgcn_s_setprio(1);                                             \
    _Pragma("unroll") for (int ks = 0; ks < 2; ++ks)                           \
      _Pragma("unroll") for (int m = 0; m < 4; ++m)                            \
        _Pragma("unroll") for (int ni = 2; ni < 4; ++ni)                       \
          acc[4 + m][ni] = MFMA(aB[m][ks], bv[ni][ks], acc[4 + m][ni]);        \
    __builtin_amdgcn_s_setprio(0);                                             \
    if ((kt) < NT - 2) asm volatile("s_waitcnt vmcnt(6)" ::: "memory");        \
    else               asm volatile("s_waitcnt vmcnt(0)" ::: "memory");        \
    __builtin_amdgcn_s_barrier();                                              \
  }

  // prologue: issue halves 0..6; wait for tile0's 4 halves (8 loads) complete
#pragma unroll
  for (int H = 0; H < 7; ++H) stage(H);
  asm volatile("s_waitcnt vmcnt(6)" ::: "memory");
  __builtin_amdgcn_s_barrier();

  for (int kt2 = 0; kt2 < NT; kt2 += 2) {
    K_TILE(kt2, 0);
    K_TILE(kt2 + 1, 1);
  }
#undef K_TILE
#undef LDF

  // epilogue: y = alpha*acc + bias.  C/D: col=l&15, row=4*(l>>4)+j (m89-verified)
  const float alpha = alpha_f[0];
#pragma unroll
  for (int ni = 0; ni < 4; ++ni) {
    const int col = tn * 256 + wc * 64 + ni * 16 + lr;
    const float bs = bias[col];
#pragma unroll
    for (int mi = 0; mi < 8; ++mi) {
      const int row = tm * 256 + wr * 128 + mi * 16 + lk * 4;
      float* Cp = C + (size_t)row * N_DIM + col;
#pragma unroll
      for (int j = 0; j < 4; ++j)
        Cp[(size_t)j * N_DIM] = alpha * acc[mi][ni][j] + bs;
    }
  }
}

extern "C" void kernel_launch(void* const* d_in, const int* in_sizes, int n_in,
                              void* d_out, int out_size, void* d_ws, size_t ws_size,
                              hipStream_t stream) {
  const float* x = (const float*)d_in[0];
  const float* w = (const float*)d_in[1];
  const float* bias = (const float*)d_in[2];
  float* out = (float*)d_out;

  char* ws = (char*)d_ws;
  double* alpha_d = (double*)ws;
  float* alpha_f = (float*)(ws + 8);
  double* partials = (double*)(ws + 16);
  u16* xb = (u16*)(ws + 65536);                 // 64 MiB (M*K bf16)
  u16* qb = (u16*)(ws + 65536 + 67108864ULL);   // 128 MiB (N*K bf16)

  reduce_abs1<<<4096, 256, 0, stream>>>(w, partials);
  reduce_abs2<<<1, 256, 0, stream>>>(partials, alpha_d, alpha_f);
  quant_w<<<32768, 256, 0, stream>>>(w, alpha_d, qb);
  conv_x<<<16384, 256, 0, stream>>>(x, xb);
  gemm256<<<2048, 512, 0, stream>>>(xb, qb, bias, alpha_f, out);
}